// Round 2
// baseline (1469.938 us; speedup 1.0000x reference)
//
#include <hip/hip_runtime.h>

#define D 128

// Transpose weight [128,128] -> Wt[k][o] = W[o][k].
__global__ void transpose_w_kernel(const float* __restrict__ w, float* __restrict__ wt) {
    int t = blockIdx.x * 256 + threadIdx.x;
    if (t < D * D) {
        int o = t >> 7;
        int k = t & 127;
        wt[k * D + o] = w[t];
    }
}

// Scatter: agg[dst] += val * x[src].  One wave per edge (grid-stride); lanes
// 0..63 handle 2 channels each (coalesced 512B gather + HW f32 atomics).
__global__ __launch_bounds__(256) void scatter_kernel(const int* __restrict__ ei,
                                                      const float* __restrict__ ev,
                                                      const float* __restrict__ x,
                                                      float* agg, int E) {
    int lane = threadIdx.x & 63;
    long long wid = (long long)blockIdx.x * 4 + (threadIdx.x >> 6);
    long long nw = (long long)gridDim.x * 4;
    for (long long e = wid; e < E; e += nw) {
        int i = ei[e];          // dst
        int j = ei[(long long)E + e];  // src
        float v = ev[e];
        float2 xv = *(const float2*)&x[(size_t)j * D + lane * 2];
        float* op = &agg[(size_t)i * D + lane * 2];
        unsafeAtomicAdd(&op[0], v * xv.x);
        unsafeAtomicAdd(&op[1], v * xv.y);
    }
}

// In-place linear: row r of `io` <- row r @ W^T.  8 rows per 256-thread block;
// each row is read and written ONLY by its own 32 lanes (same wave), so the
// in-place update has no cross-thread hazard.  Wt staged in LDS (64 KiB).
__global__ __launch_bounds__(256) void linear_inplace_kernel(float* io,
                                                             const float* __restrict__ wt,
                                                             int N) {
    __shared__ float sWt[D * D];  // 64 KiB
    int t = threadIdx.x;
    for (int i = t * 4; i < D * D; i += 256 * 4) {
        *(float4*)&sWt[i] = *(const float4*)&wt[i];
    }
    __syncthreads();

    int r = blockIdx.x * 8 + (t >> 5);
    if (r >= N) return;
    int c = (t & 31) * 4;
    float* row = io + (size_t)r * D;
    float4 acc = make_float4(0.f, 0.f, 0.f, 0.f);
#pragma unroll 8
    for (int k = 0; k < D; ++k) {
        float av = row[k];  // same addr across the row's 32 lanes -> broadcast
        float4 wv = *(const float4*)&sWt[k * D + c];
        acc.x = fmaf(av, wv.x, acc.x);
        acc.y = fmaf(av, wv.y, acc.y);
        acc.z = fmaf(av, wv.z, acc.z);
        acc.w = fmaf(av, wv.w, acc.w);
    }
    // all reads of `row` by this wave completed above (lockstep within wave)
    *(float4*)&row[c] = acc;
}

extern "C" void kernel_launch(void* const* d_in, const int* in_sizes, int n_in,
                              void* d_out, int out_size, void* d_ws, size_t ws_size,
                              hipStream_t stream) {
    const float* x = (const float*)d_in[0];
    const float* w = (const float*)d_in[1];
    const int* ei = (const int*)d_in[2];   // [2,E] int32 (harness converts int64 -> int)
    const float* ev = (const float*)d_in[3];

    int N = in_sizes[0] / D;
    int E = in_sizes[3];

    float* out = (float*)d_out;
    float* wt = (float*)d_ws;  // 64 KiB only

    // out accumulates via atomics -> zero it every call (graph-replayed).
    hipMemsetAsync(d_out, 0, (size_t)out_size * sizeof(float), stream);

    transpose_w_kernel<<<(D * D + 255) / 256, 256, 0, stream>>>(w, wt);
    scatter_kernel<<<4096, 256, 0, stream>>>(ei, ev, x, out, E);
    linear_inplace_kernel<<<(N + 7) / 8, 256, 0, stream>>>(out, wt, N);
}

// Round 3
// 468.440 us; speedup vs baseline: 3.1379x; 3.1379x over previous
//
#include <hip/hip_runtime.h>

#define D 128
#define SCAN_BLK 1024

// ---------- shared: W transpose + in-place linear ----------

__global__ void transpose_w_kernel(const float* __restrict__ w, float* __restrict__ wt) {
    int t = blockIdx.x * 256 + threadIdx.x;
    if (t < D * D) {
        int o = t >> 7;
        int k = t & 127;
        wt[k * D + o] = w[t];
    }
}

// Row r of io <- row r @ W^T.  8 rows / 256-thread block; each row touched only
// by its own 32 lanes (one wave) -> in-place safe.  Wt in LDS (64 KiB).
__global__ __launch_bounds__(256) void linear_inplace_kernel(float* io,
                                                             const float* __restrict__ wt,
                                                             int N) {
    __shared__ float sWt[D * D];
    int t = threadIdx.x;
    for (int i = t * 4; i < D * D; i += 256 * 4)
        *(float4*)&sWt[i] = *(const float4*)&wt[i];
    __syncthreads();

    int r = blockIdx.x * 8 + (t >> 5);
    if (r >= N) return;
    int c = (t & 31) * 4;
    float* row = io + (size_t)r * D;
    float4 acc = make_float4(0.f, 0.f, 0.f, 0.f);
#pragma unroll 8
    for (int k = 0; k < D; ++k) {
        float av = row[k];
        float4 wv = *(const float4*)&sWt[k * D + c];
        acc.x = fmaf(av, wv.x, acc.x);
        acc.y = fmaf(av, wv.y, acc.y);
        acc.z = fmaf(av, wv.z, acc.z);
        acc.w = fmaf(av, wv.w, acc.w);
    }
    *(float4*)&row[c] = acc;
}

// ---------- CSR build ----------

__global__ void hist_kernel(const int* __restrict__ ei, int* deg, int E) {
    int e = blockIdx.x * 256 + threadIdx.x;
    if (e < E) atomicAdd(&deg[ei[e]], 1);
}

// inclusive scan of deg per 1024-block; block total to blksum
__global__ __launch_bounds__(SCAN_BLK) void scan_blocks_kernel(const int* __restrict__ deg,
                                                               int* inscan, int* blksum, int n) {
    __shared__ int s[SCAN_BLK];
    int gid = blockIdx.x * SCAN_BLK + threadIdx.x;
    int v = (gid < n) ? deg[gid] : 0;
    s[threadIdx.x] = v;
    __syncthreads();
    for (int d = 1; d < SCAN_BLK; d <<= 1) {
        int t = (threadIdx.x >= d) ? s[threadIdx.x - d] : 0;
        __syncthreads();
        s[threadIdx.x] += t;
        __syncthreads();
    }
    if (gid < n) inscan[gid] = s[threadIdx.x];
    if (threadIdx.x == SCAN_BLK - 1) blksum[blockIdx.x] = s[SCAN_BLK - 1];
}

// exclusive scan of blksum (nblk <= 128) in one block
__global__ __launch_bounds__(128) void scan_sums_kernel(const int* __restrict__ blksum,
                                                        int* blkoff, int nblk) {
    __shared__ int s[128];
    int v = (threadIdx.x < nblk) ? blksum[threadIdx.x] : 0;
    s[threadIdx.x] = v;
    __syncthreads();
    for (int d = 1; d < 128; d <<= 1) {
        int t = (threadIdx.x >= d) ? s[threadIdx.x - d] : 0;
        __syncthreads();
        s[threadIdx.x] += t;
        __syncthreads();
    }
    if (threadIdx.x < nblk) blkoff[threadIdx.x] = s[threadIdx.x] - v;
}

__global__ void finalize_offsets_kernel(const int* __restrict__ deg,
                                        const int* __restrict__ inscan,
                                        const int* __restrict__ blkoff,
                                        int* off, int* cursor, int n, int E) {
    int gid = blockIdx.x * 256 + threadIdx.x;
    if (gid < n) {
        int o = blkoff[gid >> 10] + inscan[gid] - deg[gid];  // exclusive
        off[gid] = o;
        cursor[gid] = o;
    }
    if (gid == 0) off[n] = E;
}

__global__ void edge_scatter_kernel(const int* __restrict__ ei, const float* __restrict__ ev,
                                    int* cursor, int2* __restrict__ srt, int E) {
    int e = blockIdx.x * 256 + threadIdx.x;
    if (e < E) {
        int dst = ei[e];
        int src = ei[E + e];
        int pos = atomicAdd(&cursor[dst], 1);
        srt[pos] = make_int2(src, __float_as_int(ev[e]));
    }
}

// ---------- gather: one wave per node, no atomics ----------
__global__ __launch_bounds__(256) void gather_kernel(const int* __restrict__ off,
                                                     const int2* __restrict__ srt,
                                                     const float* __restrict__ x,
                                                     float* __restrict__ out, int N) {
    int lane = threadIdx.x & 63;
    int wid = blockIdx.x * 4 + (threadIdx.x >> 6);
    if (wid >= N) return;
    int beg = off[wid], end = off[wid + 1];
    float2 acc = make_float2(0.f, 0.f);
    int e = beg;
    // unroll-by-2: two independent x-row loads in flight
    for (; e + 1 < end; e += 2) {
        int2 sv0 = srt[e];
        int2 sv1 = srt[e + 1];
        float2 xv0 = *(const float2*)&x[(size_t)sv0.x * D + lane * 2];
        float2 xv1 = *(const float2*)&x[(size_t)sv1.x * D + lane * 2];
        float v0 = __int_as_float(sv0.y);
        float v1 = __int_as_float(sv1.y);
        acc.x = fmaf(v0, xv0.x, acc.x);
        acc.y = fmaf(v0, xv0.y, acc.y);
        acc.x = fmaf(v1, xv1.x, acc.x);
        acc.y = fmaf(v1, xv1.y, acc.y);
    }
    if (e < end) {
        int2 sv = srt[e];
        float2 xv = *(const float2*)&x[(size_t)sv.x * D + lane * 2];
        float v = __int_as_float(sv.y);
        acc.x = fmaf(v, xv.x, acc.x);
        acc.y = fmaf(v, xv.y, acc.y);
    }
    *(float2*)&out[(size_t)wid * D + lane * 2] = acc;
}

// ---------- fallback (proven R2 path) ----------
__global__ __launch_bounds__(256) void scatter_kernel(const int* __restrict__ ei,
                                                      const float* __restrict__ ev,
                                                      const float* __restrict__ x,
                                                      float* agg, int E) {
    int lane = threadIdx.x & 63;
    long long wid = (long long)blockIdx.x * 4 + (threadIdx.x >> 6);
    long long nw = (long long)gridDim.x * 4;
    for (long long e = wid; e < E; e += nw) {
        int i = ei[e];
        int j = ei[(long long)E + e];
        float v = ev[e];
        float2 xv = *(const float2*)&x[(size_t)j * D + lane * 2];
        float* op = &agg[(size_t)i * D + lane * 2];
        unsafeAtomicAdd(&op[0], v * xv.x);
        unsafeAtomicAdd(&op[1], v * xv.y);
    }
}

extern "C" void kernel_launch(void* const* d_in, const int* in_sizes, int n_in,
                              void* d_out, int out_size, void* d_ws, size_t ws_size,
                              hipStream_t stream) {
    const float* x = (const float*)d_in[0];
    const float* w = (const float*)d_in[1];
    const int* ei = (const int*)d_in[2];   // [2,E] int32 (dst row, then src row)
    const float* ev = (const float*)d_in[3];

    int N = in_sizes[0] / D;
    int E = in_sizes[3];
    int nblk = (N + SCAN_BLK - 1) / SCAN_BLK;

    float* out = (float*)d_out;

    // workspace layout
    char* p = (char*)d_ws;
    float* wt = (float*)p;              p += (size_t)D * D * sizeof(float);
    int* deg = (int*)p;                 p += (size_t)N * sizeof(int);
    int* inscan = (int*)p;              p += (size_t)N * sizeof(int);
    int* off = (int*)p;                 p += (size_t)(N + 1) * sizeof(int);
    int* cursor = (int*)p;              p += (size_t)N * sizeof(int);
    int* blksum = (int*)p;              p += (size_t)nblk * sizeof(int);
    int* blkoff = (int*)p;              p += (size_t)nblk * sizeof(int);
    p = (char*)(((uintptr_t)p + 255) & ~(uintptr_t)255);
    int2* srt = (int2*)p;               p += (size_t)E * sizeof(int2);
    size_t needed = (size_t)(p - (char*)d_ws);

    transpose_w_kernel<<<(D * D + 255) / 256, 256, 0, stream>>>(w, wt);

    if (ws_size >= needed) {
        // CSR build (counting sort by dst), then atomic-free gather
        hipMemsetAsync(deg, 0, (size_t)N * sizeof(int), stream);
        hist_kernel<<<(E + 255) / 256, 256, 0, stream>>>(ei, deg, E);
        scan_blocks_kernel<<<nblk, SCAN_BLK, 0, stream>>>(deg, inscan, blksum, N);
        scan_sums_kernel<<<1, 128, 0, stream>>>(blksum, blkoff, nblk);
        finalize_offsets_kernel<<<(N + 255) / 256, 256, 0, stream>>>(deg, inscan, blkoff,
                                                                     off, cursor, N, E);
        edge_scatter_kernel<<<(E + 255) / 256, 256, 0, stream>>>(ei, ev, cursor, srt, E);
        gather_kernel<<<(N + 3) / 4, 256, 0, stream>>>(off, srt, x, out, N);
    } else {
        // fallback: atomic scatter (R2 path)
        hipMemsetAsync(d_out, 0, (size_t)out_size * sizeof(float), stream);
        scatter_kernel<<<4096, 256, 0, stream>>>(ei, ev, x, out, E);
    }

    linear_inplace_kernel<<<(N + 7) / 8, 256, 0, stream>>>(out, wt, N);
}

// Round 4
// 362.743 us; speedup vs baseline: 4.0523x; 1.2914x over previous
//
#include <hip/hip_runtime.h>

#define D 128
#define SCAN_BLK 1024
#define BM 64
#define KC 32

// ---------- W transpose: Wt[k][o] = W[o][k] ----------
__global__ void transpose_w_kernel(const float* __restrict__ w, float* __restrict__ wt) {
    int t = blockIdx.x * 256 + threadIdx.x;
    if (t < D * D) {
        int o = t >> 7;
        int k = t & 127;
        wt[k * D + o] = w[t];
    }
}

// ---------- register-tiled in-place GEMM: io[64xD] <- io[64xD] @ Wt ----------
// 256 thr, thread tile 4 rows x 8 cols (32 acc).  A staged transposed in LDS.
__global__ __launch_bounds__(256) void linear_tiled_kernel(float* io,
                                                           const float* __restrict__ wt,
                                                           int N) {
    __shared__ float sA[KC][BM + 4];  // [k][row], stride 68: 16B-aligned rows, cheap banks
    __shared__ float sW[KC][D];       // [k][col]
    int t = threadIdx.x;
    int tc = t & 15;   // col group -> cols tc*8..+7
    int tr = t >> 4;   // row group -> rows tr*4..+3
    int row0 = blockIdx.x * BM;

    float acc[4][8];
#pragma unroll
    for (int i = 0; i < 4; ++i)
#pragma unroll
        for (int j = 0; j < 8; ++j) acc[i][j] = 0.f;

    int ldA_r = t >> 3;        // 0..31
    int ldA_k = (t & 7) * 4;   // 0..28 step 4
    int ldW_k = t >> 5;        // 0..7
    int ldW_c = (t & 31) * 4;  // 0..124 step 4

    for (int kc = 0; kc < D; kc += KC) {
        // stage A chunk (64 rows x 32 k) transposed
#pragma unroll
        for (int rr = 0; rr < BM; rr += 32) {
            int r = row0 + ldA_r + rr;
            int rcl = r < N ? r : N - 1;  // clamp (dup-read safe, in-block row)
            float4 v = *(const float4*)&io[(size_t)rcl * D + kc + ldA_k];
            sA[ldA_k + 0][ldA_r + rr] = v.x;
            sA[ldA_k + 1][ldA_r + rr] = v.y;
            sA[ldA_k + 2][ldA_r + rr] = v.z;
            sA[ldA_k + 3][ldA_r + rr] = v.w;
        }
        // stage W chunk (32 k x 128 c)
#pragma unroll
        for (int kk = 0; kk < KC; kk += 8)
            *(float4*)&sW[ldW_k + kk][ldW_c] =
                *(const float4*)&wt[(size_t)(kc + ldW_k + kk) * D + ldW_c];
        __syncthreads();

#pragma unroll 8
        for (int k = 0; k < KC; ++k) {
            float4 a = *(const float4*)&sA[k][tr * 4];
            float4 w0 = *(const float4*)&sW[k][tc * 8];
            float4 w1 = *(const float4*)&sW[k][tc * 8 + 4];
            float av[4] = {a.x, a.y, a.z, a.w};
            float wv[8] = {w0.x, w0.y, w0.z, w0.w, w1.x, w1.y, w1.z, w1.w};
#pragma unroll
            for (int i = 0; i < 4; ++i)
#pragma unroll
                for (int j = 0; j < 8; ++j)
                    acc[i][j] = fmaf(av[i], wv[j], acc[i][j]);
        }
        __syncthreads();
    }

#pragma unroll
    for (int i = 0; i < 4; ++i) {
        int r = row0 + tr * 4 + i;
        if (r < N) {
            *(float4*)&io[(size_t)r * D + tc * 8] = *(float4*)&acc[i][0];
            *(float4*)&io[(size_t)r * D + tc * 8 + 4] = *(float4*)&acc[i][4];
        }
    }
}

// ---------- CSR build ----------
__global__ void hist_kernel(const int* __restrict__ ei, int* deg, int E) {
    int e = blockIdx.x * 256 + threadIdx.x;
    if (e < E) atomicAdd(&deg[ei[e]], 1);
}

__global__ __launch_bounds__(SCAN_BLK) void scan_blocks_kernel(const int* __restrict__ deg,
                                                               int* inscan, int* blksum, int n) {
    __shared__ int s[SCAN_BLK];
    int gid = blockIdx.x * SCAN_BLK + threadIdx.x;
    int v = (gid < n) ? deg[gid] : 0;
    s[threadIdx.x] = v;
    __syncthreads();
    for (int d = 1; d < SCAN_BLK; d <<= 1) {
        int t = (threadIdx.x >= d) ? s[threadIdx.x - d] : 0;
        __syncthreads();
        s[threadIdx.x] += t;
        __syncthreads();
    }
    if (gid < n) inscan[gid] = s[threadIdx.x];
    if (threadIdx.x == SCAN_BLK - 1) blksum[blockIdx.x] = s[SCAN_BLK - 1];
}

__global__ __launch_bounds__(128) void scan_sums_kernel(const int* __restrict__ blksum,
                                                        int* blkoff, int nblk) {
    __shared__ int s[128];
    int v = (threadIdx.x < nblk) ? blksum[threadIdx.x] : 0;
    s[threadIdx.x] = v;
    __syncthreads();
    for (int d = 1; d < 128; d <<= 1) {
        int t = (threadIdx.x >= d) ? s[threadIdx.x - d] : 0;
        __syncthreads();
        s[threadIdx.x] += t;
        __syncthreads();
    }
    if (threadIdx.x < nblk) blkoff[threadIdx.x] = s[threadIdx.x] - v;
}

__global__ void finalize_offsets_kernel(const int* __restrict__ deg,
                                        const int* __restrict__ inscan,
                                        const int* __restrict__ blkoff,
                                        int* off, int* cursor, int n, int E) {
    int gid = blockIdx.x * 256 + threadIdx.x;
    if (gid < n) {
        int o = blkoff[gid >> 10] + inscan[gid] - deg[gid];
        off[gid] = o;
        cursor[gid] = o;
    }
    if (gid == 0) off[n] = E;
}

__global__ void edge_scatter_kernel(const int* __restrict__ ei, const float* __restrict__ ev,
                                    int* cursor, int2* __restrict__ srt, int E) {
    int e = blockIdx.x * 256 + threadIdx.x;
    if (e < E) {
        int dst = ei[e];
        int src = ei[E + e];
        int pos = atomicAdd(&cursor[dst], 1);
        srt[pos] = make_int2(src, __float_as_int(ev[e]));
    }
}

// ---------- gather: one wave per node, no atomics ----------
__global__ __launch_bounds__(256) void gather_kernel(const int* __restrict__ off,
                                                     const int2* __restrict__ srt,
                                                     const float* __restrict__ x,
                                                     float* __restrict__ out, int N) {
    int lane = threadIdx.x & 63;
    int wid = blockIdx.x * 4 + (threadIdx.x >> 6);
    if (wid >= N) return;
    int beg = off[wid], end = off[wid + 1];
    float2 acc = make_float2(0.f, 0.f);
    int e = beg;
    for (; e + 3 < end; e += 4) {
        int2 s0 = srt[e], s1 = srt[e + 1], s2 = srt[e + 2], s3 = srt[e + 3];
        float2 x0 = *(const float2*)&x[(size_t)s0.x * D + lane * 2];
        float2 x1 = *(const float2*)&x[(size_t)s1.x * D + lane * 2];
        float2 x2 = *(const float2*)&x[(size_t)s2.x * D + lane * 2];
        float2 x3 = *(const float2*)&x[(size_t)s3.x * D + lane * 2];
        float v0 = __int_as_float(s0.y), v1 = __int_as_float(s1.y);
        float v2 = __int_as_float(s2.y), v3 = __int_as_float(s3.y);
        acc.x = fmaf(v0, x0.x, acc.x); acc.y = fmaf(v0, x0.y, acc.y);
        acc.x = fmaf(v1, x1.x, acc.x); acc.y = fmaf(v1, x1.y, acc.y);
        acc.x = fmaf(v2, x2.x, acc.x); acc.y = fmaf(v2, x2.y, acc.y);
        acc.x = fmaf(v3, x3.x, acc.x); acc.y = fmaf(v3, x3.y, acc.y);
    }
    for (; e < end; ++e) {
        int2 sv = srt[e];
        float2 xv = *(const float2*)&x[(size_t)sv.x * D + lane * 2];
        float v = __int_as_float(sv.y);
        acc.x = fmaf(v, xv.x, acc.x);
        acc.y = fmaf(v, xv.y, acc.y);
    }
    *(float2*)&out[(size_t)wid * D + lane * 2] = acc;
}

// ---------- fallback (atomic scatter) ----------
__global__ __launch_bounds__(256) void scatter_kernel(const int* __restrict__ ei,
                                                      const float* __restrict__ ev,
                                                      const float* __restrict__ x,
                                                      float* agg, int E) {
    int lane = threadIdx.x & 63;
    long long wid = (long long)blockIdx.x * 4 + (threadIdx.x >> 6);
    long long nw = (long long)gridDim.x * 4;
    for (long long e = wid; e < E; e += nw) {
        int i = ei[e];
        int j = ei[(long long)E + e];
        float v = ev[e];
        float2 xv = *(const float2*)&x[(size_t)j * D + lane * 2];
        float* op = &agg[(size_t)i * D + lane * 2];
        unsafeAtomicAdd(&op[0], v * xv.x);
        unsafeAtomicAdd(&op[1], v * xv.y);
    }
}

extern "C" void kernel_launch(void* const* d_in, const int* in_sizes, int n_in,
                              void* d_out, int out_size, void* d_ws, size_t ws_size,
                              hipStream_t stream) {
    const float* x = (const float*)d_in[0];
    const float* w = (const float*)d_in[1];
    const int* ei = (const int*)d_in[2];   // [2,E] int32 (dst row, then src row)
    const float* ev = (const float*)d_in[3];

    int N = in_sizes[0] / D;
    int E = in_sizes[3];
    int nblk = (N + SCAN_BLK - 1) / SCAN_BLK;

    float* out = (float*)d_out;

    char* p = (char*)d_ws;
    float* wt = (float*)p;   p += (size_t)D * D * sizeof(float);
    int* deg = (int*)p;      p += (size_t)N * sizeof(int);
    int* inscan = (int*)p;   p += (size_t)N * sizeof(int);
    int* off = (int*)p;      p += (size_t)(N + 1) * sizeof(int);
    int* cursor = (int*)p;   p += (size_t)N * sizeof(int);
    int* blksum = (int*)p;   p += (size_t)nblk * sizeof(int);
    int* blkoff = (int*)p;   p += (size_t)nblk * sizeof(int);
    p = (char*)(((uintptr_t)p + 255) & ~(uintptr_t)255);
    int2* srt = (int2*)p;    p += (size_t)E * sizeof(int2);
    size_t needed = (size_t)(p - (char*)d_ws);

    transpose_w_kernel<<<(D * D + 255) / 256, 256, 0, stream>>>(w, wt);

    if (ws_size >= needed) {
        hipMemsetAsync(deg, 0, (size_t)N * sizeof(int), stream);
        hist_kernel<<<(E + 255) / 256, 256, 0, stream>>>(ei, deg, E);
        scan_blocks_kernel<<<nblk, SCAN_BLK, 0, stream>>>(deg, inscan, blksum, N);
        scan_sums_kernel<<<1, 128, 0, stream>>>(blksum, blkoff, nblk);
        finalize_offsets_kernel<<<(N + 255) / 256, 256, 0, stream>>>(deg, inscan, blkoff,
                                                                     off, cursor, N, E);
        edge_scatter_kernel<<<(E + 255) / 256, 256, 0, stream>>>(ei, ev, cursor, srt, E);
        gather_kernel<<<(N + 3) / 4, 256, 0, stream>>>(off, srt, x, out, N);
    } else {
        hipMemsetAsync(d_out, 0, (size_t)out_size * sizeof(float), stream);
        scatter_kernel<<<4096, 256, 0, stream>>>(ei, ev, x, out, E);
    }

    linear_tiled_kernel<<<(N + BM - 1) / BM, 256, 0, stream>>>(out, wt, N);
}

// Round 5
// 243.305 us; speedup vs baseline: 6.0415x; 1.4909x over previous
//
#include <hip/hip_runtime.h>

#define D 128
#define SCAN_BLK 1024
#define BM 64
#define KC 32

// ---------- W transpose: Wt[k][o] = W[o][k] ----------
__global__ void transpose_w_kernel(const float* __restrict__ w, float* __restrict__ wt) {
    int t = blockIdx.x * 256 + threadIdx.x;
    if (t < D * D) {
        int o = t >> 7;
        int k = t & 127;
        wt[k * D + o] = w[t];
    }
}

// ---------- x -> bf16 (RNE), packed 2 per uint ----------
__global__ __launch_bounds__(256) void x_to_bf16_kernel(const float* __restrict__ x,
                                                        unsigned int* __restrict__ xbf,
                                                        long long nvec /* = n/4 */) {
    long long i = (long long)blockIdx.x * 256 + threadIdx.x;
    long long stride = (long long)gridDim.x * 256;
    for (; i < nvec; i += stride) {
        float4 v = ((const float4*)x)[i];
        unsigned int b0 = __float_as_uint(v.x), b1 = __float_as_uint(v.y);
        unsigned int b2 = __float_as_uint(v.z), b3 = __float_as_uint(v.w);
        b0 = (b0 + 0x7fffu + ((b0 >> 16) & 1u)) >> 16;
        b1 = (b1 + 0x7fffu + ((b1 >> 16) & 1u)) >> 16;
        b2 = (b2 + 0x7fffu + ((b2 >> 16) & 1u)) >> 16;
        b3 = (b3 + 0x7fffu + ((b3 >> 16) & 1u)) >> 16;
        ((uint2*)xbf)[i] = make_uint2(b0 | (b1 << 16), b2 | (b3 << 16));
    }
}

// ---------- hist + rank: rank[e] = arrival order within dst segment ----------
__global__ void hist_rank_kernel(const int* __restrict__ ei, int* deg,
                                 unsigned short* __restrict__ rank, int E) {
    int e = blockIdx.x * 256 + threadIdx.x;
    if (e < E) rank[e] = (unsigned short)atomicAdd(&deg[ei[e]], 1);
}

// ---------- scans ----------
__global__ __launch_bounds__(SCAN_BLK) void scan_blocks_kernel(const int* __restrict__ deg,
                                                               int* inscan, int* blksum, int n) {
    __shared__ int s[SCAN_BLK];
    int gid = blockIdx.x * SCAN_BLK + threadIdx.x;
    int v = (gid < n) ? deg[gid] : 0;
    s[threadIdx.x] = v;
    __syncthreads();
    for (int d = 1; d < SCAN_BLK; d <<= 1) {
        int t = (threadIdx.x >= d) ? s[threadIdx.x - d] : 0;
        __syncthreads();
        s[threadIdx.x] += t;
        __syncthreads();
    }
    if (gid < n) inscan[gid] = s[threadIdx.x];
    if (threadIdx.x == SCAN_BLK - 1) blksum[blockIdx.x] = s[SCAN_BLK - 1];
}

__global__ __launch_bounds__(128) void scan_sums_kernel(const int* __restrict__ blksum,
                                                        int* blkoff, int nblk) {
    __shared__ int s[128];
    int v = (threadIdx.x < nblk) ? blksum[threadIdx.x] : 0;
    s[threadIdx.x] = v;
    __syncthreads();
    for (int d = 1; d < 128; d <<= 1) {
        int t = (threadIdx.x >= d) ? s[threadIdx.x - d] : 0;
        __syncthreads();
        s[threadIdx.x] += t;
        __syncthreads();
    }
    if (threadIdx.x < nblk) blkoff[threadIdx.x] = s[threadIdx.x] - v;
}

__global__ void finalize_offsets_kernel(const int* __restrict__ deg,
                                        const int* __restrict__ inscan,
                                        const int* __restrict__ blkoff,
                                        int* off, int n, int E) {
    int gid = blockIdx.x * 256 + threadIdx.x;
    if (gid < n) off[gid] = blkoff[gid >> 10] + inscan[gid] - deg[gid];  // exclusive
    if (gid == 0) off[n] = E;
}

// ---------- reorder edges, NO atomics: pos = off[dst] + rank[e] ----------
__global__ void edge_scatter2_kernel(const int* __restrict__ ei, const float* __restrict__ ev,
                                     const int* __restrict__ off,
                                     const unsigned short* __restrict__ rank,
                                     int2* __restrict__ srt, int E) {
    int e = blockIdx.x * 256 + threadIdx.x;
    if (e < E) {
        int dst = ei[e];
        int pos = off[dst] + (int)rank[e];
        srt[pos] = make_int2(ei[E + e], __float_as_int(ev[e]));
    }
}

// ---------- gather from bf16 table: one wave per node ----------
__global__ __launch_bounds__(256) void gather_bf16_kernel(const int* __restrict__ off,
                                                          const int2* __restrict__ srt,
                                                          const unsigned int* __restrict__ xbf,
                                                          float* __restrict__ out, int N) {
    int lane = threadIdx.x & 63;
    int wid = blockIdx.x * 4 + (threadIdx.x >> 6);
    if (wid >= N) return;
    int beg = off[wid], end = off[wid + 1];
    float2 acc = make_float2(0.f, 0.f);
    int e = beg;
    for (; e + 3 < end; e += 4) {
        int2 s0 = srt[e], s1 = srt[e + 1], s2 = srt[e + 2], s3 = srt[e + 3];
        unsigned int u0 = xbf[(size_t)s0.x * 64 + lane];
        unsigned int u1 = xbf[(size_t)s1.x * 64 + lane];
        unsigned int u2 = xbf[(size_t)s2.x * 64 + lane];
        unsigned int u3 = xbf[(size_t)s3.x * 64 + lane];
        float v0 = __int_as_float(s0.y), v1 = __int_as_float(s1.y);
        float v2 = __int_as_float(s2.y), v3 = __int_as_float(s3.y);
        acc.x = fmaf(v0, __uint_as_float(u0 << 16), acc.x);
        acc.y = fmaf(v0, __uint_as_float(u0 & 0xffff0000u), acc.y);
        acc.x = fmaf(v1, __uint_as_float(u1 << 16), acc.x);
        acc.y = fmaf(v1, __uint_as_float(u1 & 0xffff0000u), acc.y);
        acc.x = fmaf(v2, __uint_as_float(u2 << 16), acc.x);
        acc.y = fmaf(v2, __uint_as_float(u2 & 0xffff0000u), acc.y);
        acc.x = fmaf(v3, __uint_as_float(u3 << 16), acc.x);
        acc.y = fmaf(v3, __uint_as_float(u3 & 0xffff0000u), acc.y);
    }
    for (; e < end; ++e) {
        int2 sv = srt[e];
        unsigned int u = xbf[(size_t)sv.x * 64 + lane];
        float v = __int_as_float(sv.y);
        acc.x = fmaf(v, __uint_as_float(u << 16), acc.x);
        acc.y = fmaf(v, __uint_as_float(u & 0xffff0000u), acc.y);
    }
    *(float2*)&out[(size_t)wid * D + lane * 2] = acc;
}

// ---------- fp32 gather (tier-2 fallback) ----------
__global__ __launch_bounds__(256) void gather_kernel(const int* __restrict__ off,
                                                     const int2* __restrict__ srt,
                                                     const float* __restrict__ x,
                                                     float* __restrict__ out, int N) {
    int lane = threadIdx.x & 63;
    int wid = blockIdx.x * 4 + (threadIdx.x >> 6);
    if (wid >= N) return;
    int beg = off[wid], end = off[wid + 1];
    float2 acc = make_float2(0.f, 0.f);
    int e = beg;
    for (; e + 3 < end; e += 4) {
        int2 s0 = srt[e], s1 = srt[e + 1], s2 = srt[e + 2], s3 = srt[e + 3];
        float2 x0 = *(const float2*)&x[(size_t)s0.x * D + lane * 2];
        float2 x1 = *(const float2*)&x[(size_t)s1.x * D + lane * 2];
        float2 x2 = *(const float2*)&x[(size_t)s2.x * D + lane * 2];
        float2 x3 = *(const float2*)&x[(size_t)s3.x * D + lane * 2];
        float v0 = __int_as_float(s0.y), v1 = __int_as_float(s1.y);
        float v2 = __int_as_float(s2.y), v3 = __int_as_float(s3.y);
        acc.x = fmaf(v0, x0.x, acc.x); acc.y = fmaf(v0, x0.y, acc.y);
        acc.x = fmaf(v1, x1.x, acc.x); acc.y = fmaf(v1, x1.y, acc.y);
        acc.x = fmaf(v2, x2.x, acc.x); acc.y = fmaf(v2, x2.y, acc.y);
        acc.x = fmaf(v3, x3.x, acc.x); acc.y = fmaf(v3, x3.y, acc.y);
    }
    for (; e < end; ++e) {
        int2 sv = srt[e];
        float2 xv = *(const float2*)&x[(size_t)sv.x * D + lane * 2];
        float v = __int_as_float(sv.y);
        acc.x = fmaf(v, xv.x, acc.x);
        acc.y = fmaf(v, xv.y, acc.y);
    }
    *(float2*)&out[(size_t)wid * D + lane * 2] = acc;
}

// ---------- register-tiled in-place GEMM: io <- io @ Wt ----------
__global__ __launch_bounds__(256) void linear_tiled_kernel(float* io,
                                                           const float* __restrict__ wt,
                                                           int N) {
    __shared__ float sA[KC][BM + 4];
    __shared__ float sW[KC][D];
    int t = threadIdx.x;
    int tc = t & 15;
    int tr = t >> 4;
    int row0 = blockIdx.x * BM;

    float acc[4][8];
#pragma unroll
    for (int i = 0; i < 4; ++i)
#pragma unroll
        for (int j = 0; j < 8; ++j) acc[i][j] = 0.f;

    int ldA_r = t >> 3;
    int ldA_k = (t & 7) * 4;
    int ldW_k = t >> 5;
    int ldW_c = (t & 31) * 4;

    for (int kc = 0; kc < D; kc += KC) {
#pragma unroll
        for (int rr = 0; rr < BM; rr += 32) {
            int r = row0 + ldA_r + rr;
            int rcl = r < N ? r : N - 1;
            float4 v = *(const float4*)&io[(size_t)rcl * D + kc + ldA_k];
            sA[ldA_k + 0][ldA_r + rr] = v.x;
            sA[ldA_k + 1][ldA_r + rr] = v.y;
            sA[ldA_k + 2][ldA_r + rr] = v.z;
            sA[ldA_k + 3][ldA_r + rr] = v.w;
        }
#pragma unroll
        for (int kk = 0; kk < KC; kk += 8)
            *(float4*)&sW[ldW_k + kk][ldW_c] =
                *(const float4*)&wt[(size_t)(kc + ldW_k + kk) * D + ldW_c];
        __syncthreads();

#pragma unroll 8
        for (int k = 0; k < KC; ++k) {
            float4 a = *(const float4*)&sA[k][tr * 4];
            float4 w0 = *(const float4*)&sW[k][tc * 8];
            float4 w1 = *(const float4*)&sW[k][tc * 8 + 4];
            float av[4] = {a.x, a.y, a.z, a.w};
            float wv[8] = {w0.x, w0.y, w0.z, w0.w, w1.x, w1.y, w1.z, w1.w};
#pragma unroll
            for (int i = 0; i < 4; ++i)
#pragma unroll
                for (int j = 0; j < 8; ++j)
                    acc[i][j] = fmaf(av[i], wv[j], acc[i][j]);
        }
        __syncthreads();
    }

#pragma unroll
    for (int i = 0; i < 4; ++i) {
        int r = row0 + tr * 4 + i;
        if (r < N) {
            *(float4*)&io[(size_t)r * D + tc * 8] = *(float4*)&acc[i][0];
            *(float4*)&io[(size_t)r * D + tc * 8 + 4] = *(float4*)&acc[i][4];
        }
    }
}

// ---------- tier-3 fallback (atomic scatter) ----------
__global__ __launch_bounds__(256) void scatter_kernel(const int* __restrict__ ei,
                                                      const float* __restrict__ ev,
                                                      const float* __restrict__ x,
                                                      float* agg, int E) {
    int lane = threadIdx.x & 63;
    long long wid = (long long)blockIdx.x * 4 + (threadIdx.x >> 6);
    long long nw = (long long)gridDim.x * 4;
    for (long long e = wid; e < E; e += nw) {
        int i = ei[e];
        int j = ei[(long long)E + e];
        float v = ev[e];
        float2 xv = *(const float2*)&x[(size_t)j * D + lane * 2];
        float* op = &agg[(size_t)i * D + lane * 2];
        unsafeAtomicAdd(&op[0], v * xv.x);
        unsafeAtomicAdd(&op[1], v * xv.y);
    }
}

extern "C" void kernel_launch(void* const* d_in, const int* in_sizes, int n_in,
                              void* d_out, int out_size, void* d_ws, size_t ws_size,
                              hipStream_t stream) {
    const float* x = (const float*)d_in[0];
    const float* w = (const float*)d_in[1];
    const int* ei = (const int*)d_in[2];   // [2,E] int32 (dst row, then src row)
    const float* ev = (const float*)d_in[3];

    int N = in_sizes[0] / D;
    int E = in_sizes[3];
    int nblk = (N + SCAN_BLK - 1) / SCAN_BLK;

    float* out = (float*)d_out;

    // workspace layout
    char* p = (char*)d_ws;
    float* wt = (float*)p;            p += (size_t)D * D * sizeof(float);
    int* deg = (int*)p;               p += (size_t)N * sizeof(int);
    int* inscan = (int*)p;            p += (size_t)N * sizeof(int);
    int* off = (int*)p;               p += (size_t)(N + 1) * sizeof(int);
    int* blksum = (int*)p;            p += (size_t)nblk * sizeof(int);
    int* blkoff = (int*)p;            p += (size_t)nblk * sizeof(int);
    p = (char*)(((uintptr_t)p + 255) & ~(uintptr_t)255);
    unsigned short* rank = (unsigned short*)p;  p += (size_t)E * sizeof(unsigned short);
    p = (char*)(((uintptr_t)p + 255) & ~(uintptr_t)255);
    int2* srt = (int2*)p;             p += (size_t)E * sizeof(int2);
    size_t needed_t2 = (size_t)(p - (char*)d_ws);
    p = (char*)(((uintptr_t)p + 255) & ~(uintptr_t)255);
    unsigned int* xbf = (unsigned int*)p;  p += (size_t)N * (D / 2) * sizeof(unsigned int);
    size_t needed_t1 = (size_t)(p - (char*)d_ws);

    transpose_w_kernel<<<(D * D + 255) / 256, 256, 0, stream>>>(w, wt);

    if (ws_size >= needed_t2) {
        bool bf16 = (ws_size >= needed_t1);
        hipMemsetAsync(deg, 0, (size_t)N * sizeof(int), stream);
        if (bf16)
            x_to_bf16_kernel<<<2048, 256, 0, stream>>>(x, xbf, (long long)N * D / 4);
        hist_rank_kernel<<<(E + 255) / 256, 256, 0, stream>>>(ei, deg, rank, E);
        scan_blocks_kernel<<<nblk, SCAN_BLK, 0, stream>>>(deg, inscan, blksum, N);
        scan_sums_kernel<<<1, 128, 0, stream>>>(blksum, blkoff, nblk);
        finalize_offsets_kernel<<<(N + 255) / 256, 256, 0, stream>>>(deg, inscan, blkoff,
                                                                     off, N, E);
        edge_scatter2_kernel<<<(E + 255) / 256, 256, 0, stream>>>(ei, ev, off, rank, srt, E);
        if (bf16)
            gather_bf16_kernel<<<(N + 3) / 4, 256, 0, stream>>>(off, srt, xbf, out, N);
        else
            gather_kernel<<<(N + 3) / 4, 256, 0, stream>>>(off, srt, x, out, N);
    } else {
        hipMemsetAsync(d_out, 0, (size_t)out_size * sizeof(float), stream);
        scatter_kernel<<<4096, 256, 0, stream>>>(ei, ev, x, out, E);
    }

    linear_tiled_kernel<<<(N + BM - 1) / BM, 256, 0, stream>>>(out, wt, N);
}

// Round 6
// 210.463 us; speedup vs baseline: 6.9843x; 1.1560x over previous
//
#include <hip/hip_runtime.h>

#define D 128
#define SCAN_BLK 1024
#define BM 64
#define KC 32

using short8 = __attribute__((ext_vector_type(8))) short;
using floatx4 = __attribute__((ext_vector_type(4))) float;

__device__ __forceinline__ unsigned int f2bf(unsigned int b) {
    return (b + 0x7fffu + ((b >> 16) & 1u)) >> 16;  // RNE fp32->bf16 (as u16)
}

// ---------- W transpose (tier-3 VALU path): Wt[k][o] = W[o][k] ----------
__global__ void transpose_w_kernel(const float* __restrict__ w, float* __restrict__ wt) {
    int t = blockIdx.x * 256 + threadIdx.x;
    if (t < D * D) {
        int o = t >> 7;
        int k = t & 127;
        wt[k * D + o] = w[t];
    }
}

// ---------- W -> bf16, XOR-swizzled [n][k] table for MFMA B-frags ----------
// halfword index: n*128 + (k ^ ((n&7)<<3))  <=>  byte: n*256 + (2k ^ ((n&7)<<4))
__global__ void prep_wbfs_kernel(const float* __restrict__ w, unsigned short* __restrict__ wbfs) {
    int t = blockIdx.x * 256 + threadIdx.x;
    if (t < D * D) {
        int n = t >> 7, k = t & 127;
        wbfs[n * 128 + (k ^ ((n & 7) << 3))] = (unsigned short)f2bf(__float_as_uint(w[t]));
    }
}

// ---------- x -> bf16 (RNE), packed 2 per uint ----------
__global__ __launch_bounds__(256) void x_to_bf16_kernel(const float* __restrict__ x,
                                                        unsigned int* __restrict__ xbf,
                                                        long long nvec) {
    long long i = (long long)blockIdx.x * 256 + threadIdx.x;
    long long stride = (long long)gridDim.x * 256;
    for (; i < nvec; i += stride) {
        float4 v = ((const float4*)x)[i];
        unsigned int b0 = f2bf(__float_as_uint(v.x)), b1 = f2bf(__float_as_uint(v.y));
        unsigned int b2 = f2bf(__float_as_uint(v.z)), b3 = f2bf(__float_as_uint(v.w));
        ((uint2*)xbf)[i] = make_uint2(b0 | (b1 << 16), b2 | (b3 << 16));
    }
}

// ---------- hist + rank ----------
__global__ void hist_rank_kernel(const int* __restrict__ ei, int* deg,
                                 unsigned short* __restrict__ rank, int E) {
    int e = blockIdx.x * 256 + threadIdx.x;
    if (e < E) rank[e] = (unsigned short)atomicAdd(&deg[ei[e]], 1);
}

// ---------- scans ----------
__global__ __launch_bounds__(SCAN_BLK) void scan_blocks_kernel(const int* __restrict__ deg,
                                                               int* inscan, int* blksum, int n) {
    __shared__ int s[SCAN_BLK];
    int gid = blockIdx.x * SCAN_BLK + threadIdx.x;
    int v = (gid < n) ? deg[gid] : 0;
    s[threadIdx.x] = v;
    __syncthreads();
    for (int d = 1; d < SCAN_BLK; d <<= 1) {
        int t = (threadIdx.x >= d) ? s[threadIdx.x - d] : 0;
        __syncthreads();
        s[threadIdx.x] += t;
        __syncthreads();
    }
    if (gid < n) inscan[gid] = s[threadIdx.x];
    if (threadIdx.x == SCAN_BLK - 1) blksum[blockIdx.x] = s[SCAN_BLK - 1];
}

__global__ __launch_bounds__(128) void scan_sums_kernel(const int* __restrict__ blksum,
                                                        int* blkoff, int nblk) {
    __shared__ int s[128];
    int v = (threadIdx.x < nblk) ? blksum[threadIdx.x] : 0;
    s[threadIdx.x] = v;
    __syncthreads();
    for (int d = 1; d < 128; d <<= 1) {
        int t = (threadIdx.x >= d) ? s[threadIdx.x - d] : 0;
        __syncthreads();
        s[threadIdx.x] += t;
        __syncthreads();
    }
    if (threadIdx.x < nblk) blkoff[threadIdx.x] = s[threadIdx.x] - v;
}

__global__ void finalize_offsets_kernel(const int* __restrict__ deg,
                                        const int* __restrict__ inscan,
                                        const int* __restrict__ blkoff,
                                        int* off, int n, int E) {
    int gid = blockIdx.x * 256 + threadIdx.x;
    if (gid < n) off[gid] = blkoff[gid >> 10] + inscan[gid] - deg[gid];
    if (gid == 0) off[n] = E;
}

// ---------- reorder edges: pos = off[dst] + rank[e] (no atomics) ----------
__global__ void edge_scatter2_kernel(const int* __restrict__ ei, const float* __restrict__ ev,
                                     const int* __restrict__ off,
                                     const unsigned short* __restrict__ rank,
                                     int2* __restrict__ srt, int E) {
    int e = blockIdx.x * 256 + threadIdx.x;
    if (e < E) {
        int dst = ei[e];
        int pos = off[dst] + (int)rank[e];
        srt[pos] = make_int2(ei[E + e], __float_as_int(ev[e]));
    }
}

// ---------- gather from bf16 table ----------
__global__ __launch_bounds__(256) void gather_bf16_kernel(const int* __restrict__ off,
                                                          const int2* __restrict__ srt,
                                                          const unsigned int* __restrict__ xbf,
                                                          float* __restrict__ out, int N) {
    int lane = threadIdx.x & 63;
    int wid = blockIdx.x * 4 + (threadIdx.x >> 6);
    if (wid >= N) return;
    int beg = off[wid], end = off[wid + 1];
    float2 acc = make_float2(0.f, 0.f);
    int e = beg;
    for (; e + 3 < end; e += 4) {
        int2 s0 = srt[e], s1 = srt[e + 1], s2 = srt[e + 2], s3 = srt[e + 3];
        unsigned int u0 = xbf[(size_t)s0.x * 64 + lane];
        unsigned int u1 = xbf[(size_t)s1.x * 64 + lane];
        unsigned int u2 = xbf[(size_t)s2.x * 64 + lane];
        unsigned int u3 = xbf[(size_t)s3.x * 64 + lane];
        float v0 = __int_as_float(s0.y), v1 = __int_as_float(s1.y);
        float v2 = __int_as_float(s2.y), v3 = __int_as_float(s3.y);
        acc.x = fmaf(v0, __uint_as_float(u0 << 16), acc.x);
        acc.y = fmaf(v0, __uint_as_float(u0 & 0xffff0000u), acc.y);
        acc.x = fmaf(v1, __uint_as_float(u1 << 16), acc.x);
        acc.y = fmaf(v1, __uint_as_float(u1 & 0xffff0000u), acc.y);
        acc.x = fmaf(v2, __uint_as_float(u2 << 16), acc.x);
        acc.y = fmaf(v2, __uint_as_float(u2 & 0xffff0000u), acc.y);
        acc.x = fmaf(v3, __uint_as_float(u3 << 16), acc.x);
        acc.y = fmaf(v3, __uint_as_float(u3 & 0xffff0000u), acc.y);
    }
    for (; e < end; ++e) {
        int2 sv = srt[e];
        unsigned int u = xbf[(size_t)sv.x * 64 + lane];
        float v = __int_as_float(sv.y);
        acc.x = fmaf(v, __uint_as_float(u << 16), acc.x);
        acc.y = fmaf(v, __uint_as_float(u & 0xffff0000u), acc.y);
    }
    *(float2*)&out[(size_t)wid * D + lane * 2] = acc;
}

// ---------- fp32 gather (tier-2) ----------
__global__ __launch_bounds__(256) void gather_kernel(const int* __restrict__ off,
                                                     const int2* __restrict__ srt,
                                                     const float* __restrict__ x,
                                                     float* __restrict__ out, int N) {
    int lane = threadIdx.x & 63;
    int wid = blockIdx.x * 4 + (threadIdx.x >> 6);
    if (wid >= N) return;
    int beg = off[wid], end = off[wid + 1];
    float2 acc = make_float2(0.f, 0.f);
    for (int e = beg; e < end; ++e) {
        int2 sv = srt[e];
        float2 xv = *(const float2*)&x[(size_t)sv.x * D + lane * 2];
        float v = __int_as_float(sv.y);
        acc.x = fmaf(v, xv.x, acc.x);
        acc.y = fmaf(v, xv.y, acc.y);
    }
    *(float2*)&out[(size_t)wid * D + lane * 2] = acc;
}

// ---------- MFMA in-place linear: io[64 x 128] <- bf16(io) @ bf16(W)^T ----------
// A staged fp32->bf16 in XOR-swizzled LDS [m][k] (byte ^= (m&7)<<4), W from
// pre-swizzled global table.  4 waves; wave w: rows [16w,16w+16) x all 128 cols.
// Frags: A/B lane l = 8 contiguous k at row/col (l&15), k-base 8*(l>>4);
// C/D: col=l&15, row=4*(l>>4)+reg (m89-verified).
__global__ __launch_bounds__(256) void linear_mfma_kernel(float* io,
                                                          const unsigned short* __restrict__ wbfs,
                                                          int N) {
    __shared__ __align__(16) unsigned short sW[D * D];   // 32 KiB, swizzled [n][k]
    __shared__ __align__(16) unsigned short sA[BM * D];  // 16 KiB, swizzled [m][k]
    int t = threadIdx.x;
    int row0 = blockIdx.x * BM;

    // stage W (linear copy, swizzle baked into wbfs)
    {
        const uint4* src = (const uint4*)wbfs;
        uint4* dst = (uint4*)sW;
#pragma unroll
        for (int i = 0; i < 8; ++i) dst[i * 256 + t] = src[i * 256 + t];
    }
    // stage A: read fp32 rows coalesced, convert, swizzled 8B LDS writes
#pragma unroll
    for (int it = 0; it < 8; ++it) {
        int idx = it * 1024 + t * 4;
        int m = idx >> 7;
        int k0 = idx & 127;
        int r = row0 + m;
        int rcl = r < N ? r : N - 1;
        float4 v = *(const float4*)&io[(size_t)rcl * D + k0];
        unsigned int b0 = f2bf(__float_as_uint(v.x)), b1 = f2bf(__float_as_uint(v.y));
        unsigned int b2 = f2bf(__float_as_uint(v.z)), b3 = f2bf(__float_as_uint(v.w));
        int byteoff = m * 256 + ((k0 * 2) ^ ((m & 7) << 4));
        *(uint2*)((char*)sA + byteoff) = make_uint2(b0 | (b1 << 16), b2 | (b3 << 16));
    }
    __syncthreads();

    int lane = t & 63;
    int w = t >> 6;
    int lm = 16 * w + (lane & 15);
    int ln = lane & 15;
    int kg = lane >> 4;

    floatx4 acc[8];
#pragma unroll
    for (int nt = 0; nt < 8; ++nt) acc[nt] = (floatx4){0.f, 0.f, 0.f, 0.f};

#pragma unroll
    for (int ks = 0; ks < 4; ++ks) {
        int kbyte = ks * 64 + kg * 16;
        short8 a = *(const short8*)((const char*)sA + lm * 256 + (kbyte ^ ((lm & 7) << 4)));
#pragma unroll
        for (int nt = 0; nt < 8; ++nt) {
            int n = nt * 16 + ln;
            short8 b = *(const short8*)((const char*)sW + n * 256 + (kbyte ^ ((n & 7) << 4)));
            acc[nt] = __builtin_amdgcn_mfma_f32_16x16x32_bf16(a, b, acc[nt], 0, 0, 0);
        }
    }

    int rbase = row0 + 16 * w + 4 * kg;
#pragma unroll
    for (int nt = 0; nt < 8; ++nt) {
#pragma unroll
        for (int r = 0; r < 4; ++r) {
            int row = rbase + r;
            if (row < N) io[(size_t)row * D + nt * 16 + ln] = acc[nt][r];
        }
    }
}

// ---------- VALU tiled GEMM (tier-3 fallback) ----------
__global__ __launch_bounds__(256) void linear_tiled_kernel(float* io,
                                                           const float* __restrict__ wt,
                                                           int N) {
    __shared__ float sA[KC][BM + 4];
    __shared__ float sW2[KC][D];
    int t = threadIdx.x;
    int tc = t & 15;
    int tr = t >> 4;
    int row0 = blockIdx.x * BM;

    float acc[4][8];
#pragma unroll
    for (int i = 0; i < 4; ++i)
#pragma unroll
        for (int j = 0; j < 8; ++j) acc[i][j] = 0.f;

    int ldA_r = t >> 3;
    int ldA_k = (t & 7) * 4;
    int ldW_k = t >> 5;
    int ldW_c = (t & 31) * 4;

    for (int kc = 0; kc < D; kc += KC) {
#pragma unroll
        for (int rr = 0; rr < BM; rr += 32) {
            int r = row0 + ldA_r + rr;
            int rcl = r < N ? r : N - 1;
            float4 v = *(const float4*)&io[(size_t)rcl * D + kc + ldA_k];
            sA[ldA_k + 0][ldA_r + rr] = v.x;
            sA[ldA_k + 1][ldA_r + rr] = v.y;
            sA[ldA_k + 2][ldA_r + rr] = v.z;
            sA[ldA_k + 3][ldA_r + rr] = v.w;
        }
#pragma unroll
        for (int kk = 0; kk < KC; kk += 8)
            *(float4*)&sW2[ldW_k + kk][ldW_c] =
                *(const float4*)&wt[(size_t)(kc + ldW_k + kk) * D + ldW_c];
        __syncthreads();

#pragma unroll 8
        for (int k = 0; k < KC; ++k) {
            float4 a = *(const float4*)&sA[k][tr * 4];
            float4 w0 = *(const float4*)&sW2[k][tc * 8];
            float4 w1 = *(const float4*)&sW2[k][tc * 8 + 4];
            float av[4] = {a.x, a.y, a.z, a.w};
            float wv[8] = {w0.x, w0.y, w0.z, w0.w, w1.x, w1.y, w1.z, w1.w};
#pragma unroll
            for (int i = 0; i < 4; ++i)
#pragma unroll
                for (int j = 0; j < 8; ++j)
                    acc[i][j] = fmaf(av[i], wv[j], acc[i][j]);
        }
        __syncthreads();
    }

#pragma unroll
    for (int i = 0; i < 4; ++i) {
        int r = row0 + tr * 4 + i;
        if (r < N) {
            *(float4*)&io[(size_t)r * D + tc * 8] = *(float4*)&acc[i][0];
            *(float4*)&io[(size_t)r * D + tc * 8 + 4] = *(float4*)&acc[i][4];
        }
    }
}

// ---------- tier-3 fallback (atomic scatter) ----------
__global__ __launch_bounds__(256) void scatter_kernel(const int* __restrict__ ei,
                                                      const float* __restrict__ ev,
                                                      const float* __restrict__ x,
                                                      float* agg, int E) {
    int lane = threadIdx.x & 63;
    long long wid = (long long)blockIdx.x * 4 + (threadIdx.x >> 6);
    long long nw = (long long)gridDim.x * 4;
    for (long long e = wid; e < E; e += nw) {
        int i = ei[e];
        int j = ei[(long long)E + e];
        float v = ev[e];
        float2 xv = *(const float2*)&x[(size_t)j * D + lane * 2];
        float* op = &agg[(size_t)i * D + lane * 2];
        unsafeAtomicAdd(&op[0], v * xv.x);
        unsafeAtomicAdd(&op[1], v * xv.y);
    }
}

extern "C" void kernel_launch(void* const* d_in, const int* in_sizes, int n_in,
                              void* d_out, int out_size, void* d_ws, size_t ws_size,
                              hipStream_t stream) {
    const float* x = (const float*)d_in[0];
    const float* w = (const float*)d_in[1];
    const int* ei = (const int*)d_in[2];   // [2,E] int32 (dst row, then src row)
    const float* ev = (const float*)d_in[3];

    int N = in_sizes[0] / D;
    int E = in_sizes[3];
    int nblk = (N + SCAN_BLK - 1) / SCAN_BLK;

    float* out = (float*)d_out;

    // workspace layout
    char* p = (char*)d_ws;
    float* wt = (float*)p;            p += (size_t)D * D * sizeof(float);
    unsigned short* wbfs = (unsigned short*)p;  p += (size_t)D * D * sizeof(unsigned short);
    int* deg = (int*)p;               p += (size_t)N * sizeof(int);
    int* inscan = (int*)p;            p += (size_t)N * sizeof(int);
    int* off = (int*)p;               p += (size_t)(N + 1) * sizeof(int);
    int* blksum = (int*)p;            p += (size_t)nblk * sizeof(int);
    int* blkoff = (int*)p;            p += (size_t)nblk * sizeof(int);
    p = (char*)(((uintptr_t)p + 255) & ~(uintptr_t)255);
    unsigned short* rank = (unsigned short*)p;  p += (size_t)E * sizeof(unsigned short);
    p = (char*)(((uintptr_t)p + 255) & ~(uintptr_t)255);
    int2* srt = (int2*)p;             p += (size_t)E * sizeof(int2);
    size_t needed_t2 = (size_t)(p - (char*)d_ws);
    p = (char*)(((uintptr_t)p + 255) & ~(uintptr_t)255);
    unsigned int* xbf = (unsigned int*)p;  p += (size_t)N * (D / 2) * sizeof(unsigned int);
    size_t needed_t1 = (size_t)(p - (char*)d_ws);

    int gemm_blocks = (N + BM - 1) / BM;

    if (ws_size >= needed_t2) {
        bool bf16 = (ws_size >= needed_t1);
        prep_wbfs_kernel<<<(D * D + 255) / 256, 256, 0, stream>>>(w, wbfs);
        hipMemsetAsync(deg, 0, (size_t)N * sizeof(int), stream);
        if (bf16)
            x_to_bf16_kernel<<<2048, 256, 0, stream>>>(x, xbf, (long long)N * D / 4);
        hist_rank_kernel<<<(E + 255) / 256, 256, 0, stream>>>(ei, deg, rank, E);
        scan_blocks_kernel<<<nblk, SCAN_BLK, 0, stream>>>(deg, inscan, blksum, N);
        scan_sums_kernel<<<1, 128, 0, stream>>>(blksum, blkoff, nblk);
        finalize_offsets_kernel<<<(N + 255) / 256, 256, 0, stream>>>(deg, inscan, blkoff,
                                                                     off, N, E);
        edge_scatter2_kernel<<<(E + 255) / 256, 256, 0, stream>>>(ei, ev, off, rank, srt, E);
        if (bf16)
            gather_bf16_kernel<<<(N + 3) / 4, 256, 0, stream>>>(off, srt, xbf, out, N);
        else
            gather_kernel<<<(N + 3) / 4, 256, 0, stream>>>(off, srt, x, out, N);
        linear_mfma_kernel<<<gemm_blocks, 256, 0, stream>>>(out, wbfs, N);
    } else {
        transpose_w_kernel<<<(D * D + 255) / 256, 256, 0, stream>>>(w, wt);
        hipMemsetAsync(d_out, 0, (size_t)out_size * sizeof(float), stream);
        scatter_kernel<<<4096, 256, 0, stream>>>(ei, ev, x, out, E);
        linear_tiled_kernel<<<gemm_blocks, 256, 0, stream>>>(out, wt, N);
    }
}